// Round 1
// baseline (1985.874 us; speedup 1.0000x reference)
//
#include <hip/hip_runtime.h>

#define NB 8192   // tokens
#define NC 1024   // model dim
#define NE 8      // experts
#define NK 4      // top-k
#define NH 4096   // hidden dim
constexpr int ROWCAP = NB * NK + NE * 128;  // padded routed-row capacity

typedef _Float16 f16;
typedef _Float16 f16x8 __attribute__((ext_vector_type(8)));
typedef _Float16 f16x4 __attribute__((ext_vector_type(4)));
typedef float    f32x4 __attribute__((ext_vector_type(4)));

__device__ __forceinline__ void async_cp16(const f16* g, f16* l) {
    __builtin_amdgcn_global_load_lds((const __attribute__((address_space(1))) void*)g,
                                     (__attribute__((address_space(3))) void*)l, 16, 0, 0);
}

__device__ __forceinline__ float quick_gelu(float v) {
    return v / (1.f + __expf(-1.702f * v));
}

// ---------------- cast x (fp32 -> fp16) ----------------
__global__ void cast_x_k(const float* __restrict__ x, f16* __restrict__ x16) {
    int i = blockIdx.x * 256 + threadIdx.x;
    float4 v = ((const float4*)x)[i];
    f16x4 h = { (f16)v.x, (f16)v.y, (f16)v.z, (f16)v.w };
    ((f16x4*)x16)[i] = h;
}

// ------------- transpose + cast: in [E][R][S] fp32 -> out [E][S][R] fp16 -------------
__global__ void transpose_cast_k(const float* __restrict__ in, f16* __restrict__ out,
                                 int R, int S) {
    __shared__ f16 tile[32][33];
    int e = blockIdx.z;
    long base = (long)e * R * S;
    int s0 = blockIdx.x * 32, r0 = blockIdx.y * 32;
    int tx = threadIdx.x & 31, ty = threadIdx.x >> 5;  // 32 x 8
    #pragma unroll
    for (int i = 0; i < 32; i += 8)
        tile[ty + i][tx] = (f16)in[base + (long)(r0 + ty + i) * S + s0 + tx];
    __syncthreads();
    #pragma unroll
    for (int i = 0; i < 32; i += 8)
        out[base + (long)(s0 + ty + i) * R + r0 + tx] = tile[tx][ty + i];
}

// ---------------- gating: logits -> softmax -> top4 -> slot assignment ----------------
__global__ void gating_k(const float* __restrict__ x, const float* __restrict__ Wg,
                         const float* __restrict__ bg, int* __restrict__ counts,
                         int* __restrict__ tokmap, int* __restrict__ eids,
                         int* __restrict__ slots, float* __restrict__ gatew) {
    int b = blockIdx.x, t = threadIdx.x;
    float acc[NE] = {};
    float4 xv = ((const float4*)(x + (long)b * NC))[t];
    const float* wr = Wg + (long)t * 4 * NE;
    #pragma unroll
    for (int j = 0; j < 4; j++) {
        float xj = ((const float*)&xv)[j];
        #pragma unroll
        for (int e2 = 0; e2 < NE; e2++) acc[e2] += xj * wr[j * NE + e2];
    }
    #pragma unroll
    for (int e2 = 0; e2 < NE; e2++)
        #pragma unroll
        for (int off = 32; off; off >>= 1) acc[e2] += __shfl_down(acc[e2], off);
    __shared__ float red[4][NE];
    int lane = t & 63, w = t >> 6;
    if (lane == 0)
        for (int e2 = 0; e2 < NE; e2++) red[w][e2] = acc[e2];
    __syncthreads();
    if (t == 0) {
        float l[NE];
        float m = -1e30f;
        for (int e2 = 0; e2 < NE; e2++) {
            l[e2] = red[0][e2] + red[1][e2] + red[2][e2] + red[3][e2] + bg[e2];
            m = fmaxf(m, l[e2]);
        }
        float p[NE], sum = 0.f;
        for (int e2 = 0; e2 < NE; e2++) { p[e2] = __expf(l[e2] - m); sum += p[e2]; }
        float inv = 1.f / sum;
        for (int e2 = 0; e2 < NE; e2++) p[e2] *= inv;
        bool taken[NE] = {};
        for (int k = 0; k < NK; k++) {
            int be = 0; float bv = -1e30f;
            for (int e2 = 0; e2 < NE; e2++)
                if (!taken[e2] && p[e2] > bv) { bv = p[e2]; be = e2; }
            taken[be] = true;
            int slot = atomicAdd(&counts[be], 1);
            tokmap[be * NB + slot] = b;
            eids[b * NK + k] = be;
            slots[b * NK + k] = slot;
            gatew[b * NK + k] = bv;
        }
    }
}

// ---------------- padded prefix offsets ----------------
__global__ void offsets_k(const int* __restrict__ counts, int* __restrict__ offp) {
    if (threadIdx.x == 0 && blockIdx.x == 0) {
        int o = 0;
        for (int e = 0; e < NE; e++) { offp[e] = o; o += ((counts[e] + 127) >> 7) << 7; }
    }
}

// ---------------- GEMM: Out[row,n] = gelu(sum_k A[row,k]*Bt[e,n,k] + bias[e,n]) ----------------
// A rows gathered via tokmap (gather=1, stride Kd) or dense at offp[e] (gather=0).
__global__ __launch_bounds__(256) void gemm_f16(
    const f16* __restrict__ A, const f16* __restrict__ Bt,
    const float* __restrict__ bias, f16* __restrict__ Out,
    const int* __restrict__ counts, const int* __restrict__ offp,
    const int* __restrict__ tokmap, int Kd, int N, int gather) {
    int e = blockIdx.z;
    int cnt = counts[e];
    int m0 = blockIdx.x << 7;
    if (m0 >= cnt) return;
    int n0 = blockIdx.y << 7;
    int base = offp[e];

    __shared__ __align__(16) f16 At[128 * 32];
    __shared__ __align__(16) f16 Bs[128 * 32];

    int t = threadIdx.x;
    int lane = t & 63;
    int w = t >> 6;
    int wm = (w >> 1) << 6, wn = (w & 1) << 6;

    // staging: thread t covers tile row t/4 (and +64), k-offset (t%4)*8
    int sr = m0 + (t >> 2);
    int sc = (t & 3) << 3;
    int ca = sr < cnt - 1 ? sr : cnt - 1;
    int cb = sr + 64 < cnt - 1 ? sr + 64 : cnt - 1;
    long arow0, arow1;
    if (gather) { arow0 = tokmap[e * NB + ca]; arow1 = tokmap[e * NB + cb]; }
    else        { arow0 = base + ca;           arow1 = base + cb; }
    const f16* ap0 = A + arow0 * (long)Kd + sc;
    const f16* ap1 = A + arow1 * (long)Kd + sc;
    const f16* bp0 = Bt + ((long)e * N + n0 + (t >> 2)) * (long)Kd + sc;
    const f16* bp1 = bp0 + (long)64 * Kd;

    f32x4 acc[4][4] = {};
    int ml = lane & 15, kq = (lane >> 4) << 3;

    for (int k0 = 0; k0 < Kd; k0 += 32) {
        async_cp16(ap0 + k0, &At[t * 8]);
        async_cp16(ap1 + k0, &At[2048 + t * 8]);
        async_cp16(bp0 + k0, &Bs[t * 8]);
        async_cp16(bp1 + k0, &Bs[2048 + t * 8]);
        __syncthreads();
        f16x8 af[4], bf[4];
        #pragma unroll
        for (int mi = 0; mi < 4; mi++) af[mi] = *(const f16x8*)&At[(wm + mi * 16 + ml) * 32 + kq];
        #pragma unroll
        for (int ni = 0; ni < 4; ni++) bf[ni] = *(const f16x8*)&Bs[(wn + ni * 16 + ml) * 32 + kq];
        #pragma unroll
        for (int mi = 0; mi < 4; mi++)
            #pragma unroll
            for (int ni = 0; ni < 4; ni++)
                acc[mi][ni] = __builtin_amdgcn_mfma_f32_16x16x32_f16(af[mi], bf[ni], acc[mi][ni], 0, 0, 0);
        __syncthreads();
    }

    int rq = (lane >> 4) << 2;
    #pragma unroll
    for (int ni = 0; ni < 4; ni++) {
        int col = n0 + wn + ni * 16 + ml;
        float bv = bias[(long)e * N + col];
        #pragma unroll
        for (int mi = 0; mi < 4; mi++) {
            int r0 = m0 + wm + mi * 16 + rq;
            #pragma unroll
            for (int rr = 0; rr < 4; rr++) {
                int row = r0 + rr;
                if (row < cnt) {
                    float v = acc[mi][ni][rr] + bv;
                    Out[(long)(base + row) * N + col] = (f16)quick_gelu(v);
                }
            }
        }
    }
}

// ---------------- LayerNorm + weighted top-4 combine ----------------
__global__ void ln_combine_k(const f16* __restrict__ y16, const float* __restrict__ lng,
                             const float* __restrict__ lnb, const int* __restrict__ eids,
                             const int* __restrict__ slots, const float* __restrict__ gatew,
                             const int* __restrict__ offp, float* __restrict__ out) {
    int b = blockIdx.x, t = threadIdx.x;
    int lane = t & 63, w = t >> 6;
    __shared__ float red[4][2];
    float o[4] = {0.f, 0.f, 0.f, 0.f};
    int c0 = t * 4;
    for (int k = 0; k < NK; k++) {
        int e = eids[b * NK + k];
        long r = offp[e] + slots[b * NK + k];
        float wk = gatew[b * NK + k];
        f16x4 hv = *(const f16x4*)(y16 + r * NC + c0);
        float v[4];
        #pragma unroll
        for (int j = 0; j < 4; j++) v[j] = (float)hv[j];
        float s = v[0] + v[1] + v[2] + v[3];
        float ss = v[0] * v[0] + v[1] * v[1] + v[2] * v[2] + v[3] * v[3];
        #pragma unroll
        for (int off = 32; off; off >>= 1) { s += __shfl_down(s, off); ss += __shfl_down(ss, off); }
        if (lane == 0) { red[w][0] = s; red[w][1] = ss; }
        __syncthreads();
        float S  = red[0][0] + red[1][0] + red[2][0] + red[3][0];
        float SS = red[0][1] + red[1][1] + red[2][1] + red[3][1];
        float mu = S * (1.f / NC);
        float var = SS * (1.f / NC) - mu * mu;
        float rs = rsqrtf(var + 1e-6f);
        #pragma unroll
        for (int j = 0; j < 4; j++) {
            float g  = lng[(long)e * NC + c0 + j];
            float bb = lnb[(long)e * NC + c0 + j];
            o[j] += wk * ((v[j] - mu) * rs * g + bb);
        }
        __syncthreads();
    }
    float4 ov = {o[0], o[1], o[2], o[3]};
    ((float4*)(out + (long)b * NC))[t] = ov;
}

extern "C" void kernel_launch(void* const* d_in, const int* in_sizes, int n_in,
                              void* d_out, int out_size, void* d_ws, size_t ws_size,
                              hipStream_t stream) {
    const float* x   = (const float*)d_in[0];
    const float* W1  = (const float*)d_in[1];
    const float* b1  = (const float*)d_in[2];
    const float* W2  = (const float*)d_in[3];
    const float* b2  = (const float*)d_in[4];
    const float* lng = (const float*)d_in[5];
    const float* lnb = (const float*)d_in[6];
    const float* Wg  = (const float*)d_in[7];
    const float* bg  = (const float*)d_in[8];
    float* out = (float*)d_out;

    char* ws = (char*)d_ws;
    size_t o = 0;
    auto take = [&](size_t bytes) { char* p = ws + o; o += (bytes + 255) & ~(size_t)255; return p; };
    f16*   x16    = (f16*)take((size_t)NB * NC * 2);
    f16*   w1t    = (f16*)take((size_t)NE * NH * NC * 2);   // [E][H][C]
    f16*   w2t    = (f16*)take((size_t)NE * NC * NH * 2);   // [E][C][H]
    f16*   h16    = (f16*)take((size_t)ROWCAP * NH * 2);
    f16*   y16    = (f16*)take((size_t)ROWCAP * NC * 2);
    int*   tokmap = (int*)take((size_t)NE * NB * 4);
    int*   eids   = (int*)take((size_t)NB * NK * 4);
    int*   slots  = (int*)take((size_t)NB * NK * 4);
    float* gatew  = (float*)take((size_t)NB * NK * 4);
    int*   counts = (int*)take(256);
    int*   offp   = (int*)take(256);
    // total ~475 MiB — requires ws_size >= that; fallback plan if the bench faults.

    hipMemsetAsync(counts, 0, NE * sizeof(int), stream);
    cast_x_k<<<NB * NC / 1024, 256, 0, stream>>>(x, x16);
    transpose_cast_k<<<dim3(NH / 32, NC / 32, NE), 256, 0, stream>>>(W1, w1t, NC, NH);
    transpose_cast_k<<<dim3(NC / 32, NH / 32, NE), 256, 0, stream>>>(W2, w2t, NH, NC);
    gating_k<<<NB, 256, 0, stream>>>(x, Wg, bg, counts, tokmap, eids, slots, gatew);
    offsets_k<<<1, 64, 0, stream>>>(counts, offp);
    gemm_f16<<<dim3(64, NH / 128, NE), 256, 0, stream>>>(x16, w1t, b1, h16, counts, offp, tokmap, NC, NH, 1);
    gemm_f16<<<dim3(64, NC / 128, NE), 256, 0, stream>>>(h16, w2t, b2, y16, counts, offp, tokmap, NH, NC, 0);
    ln_combine_k<<<NB, 256, 0, stream>>>(y16, lng, lnb, eids, slots, gatew, offp, out);
}

// Round 2
// 1921.494 us; speedup vs baseline: 1.0335x; 1.0335x over previous
//
#include <hip/hip_runtime.h>

#define NB 8192   // tokens
#define NC 1024   // model dim
#define NE 8      // experts
#define NK 4      // top-k
#define NH 4096   // hidden dim
constexpr int ROWCAP = NB * NK + NE * 128;  // padded routed-row capacity

typedef _Float16 f16;
typedef _Float16 f16x8 __attribute__((ext_vector_type(8)));
typedef _Float16 f16x4 __attribute__((ext_vector_type(4)));
typedef float    f32x4 __attribute__((ext_vector_type(4)));

__device__ __forceinline__ void async_cp16(const f16* g, f16* l) {
    __builtin_amdgcn_global_load_lds((const __attribute__((address_space(1))) void*)g,
                                     (__attribute__((address_space(3))) void*)l, 16, 0, 0);
}

__device__ __forceinline__ float quick_gelu(float v) {
    return v / (1.f + __expf(-1.702f * v));
}

// ------------- transpose + cast: in [E][R][S] fp32 -> out [E][S][R] fp16 -------------
__global__ void transpose_cast_k(const float* __restrict__ in, f16* __restrict__ out,
                                 int R, int S) {
    __shared__ f16 tile[32][33];
    int e = blockIdx.z;
    long base = (long)e * R * S;
    int s0 = blockIdx.x * 32, r0 = blockIdx.y * 32;
    int tx = threadIdx.x & 31, ty = threadIdx.x >> 5;  // 32 x 8
    #pragma unroll
    for (int i = 0; i < 32; i += 8)
        tile[ty + i][tx] = (f16)in[base + (long)(r0 + ty + i) * S + s0 + tx];
    __syncthreads();
    #pragma unroll
    for (int i = 0; i < 32; i += 8)
        out[base + (long)(s0 + ty + i) * R + r0 + tx] = tile[tx][ty + i];
}

// ---- gating: logits -> softmax -> top4 -> slot assignment; also casts x -> fp16 ----
__global__ void gating_k(const float* __restrict__ x, const float* __restrict__ Wg,
                         const float* __restrict__ bg, int* __restrict__ counts,
                         int* __restrict__ tokmap, int* __restrict__ eids,
                         int* __restrict__ slots, float* __restrict__ gatew,
                         f16* __restrict__ x16) {
    int b = blockIdx.x, t = threadIdx.x;
    float acc[NE] = {};
    float4 xv = ((const float4*)(x + (long)b * NC))[t];
    // fused cast: x -> fp16 (same coalesced footprint)
    f16x4 hx = { (f16)xv.x, (f16)xv.y, (f16)xv.z, (f16)xv.w };
    ((f16x4*)(x16 + (long)b * NC))[t] = hx;
    const float* wr = Wg + (long)t * 4 * NE;
    #pragma unroll
    for (int j = 0; j < 4; j++) {
        float xj = ((const float*)&xv)[j];
        #pragma unroll
        for (int e2 = 0; e2 < NE; e2++) acc[e2] += xj * wr[j * NE + e2];
    }
    #pragma unroll
    for (int e2 = 0; e2 < NE; e2++)
        #pragma unroll
        for (int off = 32; off; off >>= 1) acc[e2] += __shfl_down(acc[e2], off);
    __shared__ float red[4][NE];
    int lane = t & 63, w = t >> 6;
    if (lane == 0)
        for (int e2 = 0; e2 < NE; e2++) red[w][e2] = acc[e2];
    __syncthreads();
    if (t == 0) {
        float l[NE];
        float m = -1e30f;
        for (int e2 = 0; e2 < NE; e2++) {
            l[e2] = red[0][e2] + red[1][e2] + red[2][e2] + red[3][e2] + bg[e2];
            m = fmaxf(m, l[e2]);
        }
        float p[NE], sum = 0.f;
        for (int e2 = 0; e2 < NE; e2++) { p[e2] = __expf(l[e2] - m); sum += p[e2]; }
        float inv = 1.f / sum;
        for (int e2 = 0; e2 < NE; e2++) p[e2] *= inv;
        bool taken[NE] = {};
        for (int k = 0; k < NK; k++) {
            int be = 0; float bv = -1e30f;
            for (int e2 = 0; e2 < NE; e2++)
                if (!taken[e2] && p[e2] > bv) { bv = p[e2]; be = e2; }
            taken[be] = true;
            int slot = atomicAdd(&counts[be], 1);
            tokmap[be * NB + slot] = b;
            eids[b * NK + k] = be;
            slots[b * NK + k] = slot;
            gatew[b * NK + k] = bv;
        }
    }
}

// ---------------- padded prefix offsets ----------------
__global__ void offsets_k(const int* __restrict__ counts, int* __restrict__ offp) {
    if (threadIdx.x == 0 && blockIdx.x == 0) {
        int o = 0;
        for (int e = 0; e < NE; e++) { offp[e] = o; o += ((counts[e] + 127) >> 7) << 7; }
    }
}

// ---------------- GEMM: Out[row,n] = gelu(sum_k A[row,k]*Bt[e,n,k] + bias[e,n]) ----------------
// A rows gathered via tokmap (gather=1, stride Kd) or dense at offp[e] (gather=0).
// LDS tiles use an XOR chunk swizzle: chunk c of row r lives at slot c ^ ((r>>1)&3).
// Staging permutes the *global source* chunk per thread (LDS dests stay lane-contiguous,
// as required by global_load_lds); fragment reads then cover all 32 banks uniformly.
__global__ __launch_bounds__(256) void gemm_f16(
    const f16* __restrict__ A, const f16* __restrict__ Bt,
    const float* __restrict__ bias, f16* __restrict__ Out,
    const int* __restrict__ counts, const int* __restrict__ offp,
    const int* __restrict__ tokmap, int Kd, int N, int gather) {
    int e = blockIdx.z;
    int cnt = counts[e];
    int m0 = blockIdx.x << 7;
    if (m0 >= cnt) return;
    int n0 = blockIdx.y << 7;
    int base = offp[e];

    __shared__ __align__(16) f16 At[128 * 32];
    __shared__ __align__(16) f16 Bs[128 * 32];

    int t = threadIdx.x;
    int lane = t & 63;
    int w = t >> 6;
    int wm = (w >> 1) << 6, wn = (w & 1) << 6;

    // staging: thread t fills LDS slot (row=t>>2, slot=t&3); source chunk is
    // c = (t&3) ^ swz(row), swz(row) = (row>>1)&3 = (t>>3)&3 (same for row+64).
    int sr = m0 + (t >> 2);
    int sc = (((t & 3) ^ ((t >> 3) & 3)) << 3);
    int ca = sr < cnt - 1 ? sr : cnt - 1;
    int cb = sr + 64 < cnt - 1 ? sr + 64 : cnt - 1;
    long arow0, arow1;
    if (gather) { arow0 = tokmap[e * NB + ca]; arow1 = tokmap[e * NB + cb]; }
    else        { arow0 = base + ca;           arow1 = base + cb; }
    const f16* ap0 = A + arow0 * (long)Kd + sc;
    const f16* ap1 = A + arow1 * (long)Kd + sc;
    const f16* bp0 = Bt + ((long)e * N + n0 + (t >> 2)) * (long)Kd + sc;
    const f16* bp1 = bp0 + (long)64 * Kd;

    f32x4 acc[4][4] = {};
    int ml = lane & 15;
    // fragment read slot: q ^ swz(row); row = {wm,wn}+mi*16+ml and wm/wn/mi*16 are
    // multiples of 16 so swz(row) = (ml>>1)&3 — one per-lane constant for all 8 frags.
    int sxq = (((lane >> 4) ^ ((ml >> 1) & 3)) << 3);
    const f16* ard[4];
    const f16* brd[4];
    #pragma unroll
    for (int mi = 0; mi < 4; mi++) ard[mi] = &At[(wm + mi * 16 + ml) * 32 + sxq];
    #pragma unroll
    for (int ni = 0; ni < 4; ni++) brd[ni] = &Bs[(wn + ni * 16 + ml) * 32 + sxq];
    f16* la0 = &At[t * 8];
    f16* la1 = &At[2048 + t * 8];
    f16* lb0 = &Bs[t * 8];
    f16* lb1 = &Bs[2048 + t * 8];

    for (int k0 = 0; k0 < Kd; k0 += 32) {
        async_cp16(ap0, la0); ap0 += 32;
        async_cp16(ap1, la1); ap1 += 32;
        async_cp16(bp0, lb0); bp0 += 32;
        async_cp16(bp1, lb1); bp1 += 32;
        __syncthreads();
        f16x8 af[4], bf[4];
        #pragma unroll
        for (int mi = 0; mi < 4; mi++) af[mi] = *(const f16x8*)ard[mi];
        #pragma unroll
        for (int ni = 0; ni < 4; ni++) bf[ni] = *(const f16x8*)brd[ni];
        #pragma unroll
        for (int mi = 0; mi < 4; mi++)
            #pragma unroll
            for (int ni = 0; ni < 4; ni++)
                acc[mi][ni] = __builtin_amdgcn_mfma_f32_16x16x32_f16(af[mi], bf[ni], acc[mi][ni], 0, 0, 0);
        __syncthreads();
    }

    int rq = (lane >> 4) << 2;
    #pragma unroll
    for (int ni = 0; ni < 4; ni++) {
        int col = n0 + wn + ni * 16 + ml;
        float bv = bias[(long)e * N + col];
        #pragma unroll
        for (int mi = 0; mi < 4; mi++) {
            int r0 = m0 + wm + mi * 16 + rq;
            #pragma unroll
            for (int rr = 0; rr < 4; rr++) {
                int row = r0 + rr;
                if (row < cnt) {
                    float v = acc[mi][ni][rr] + bv;
                    Out[(long)(base + row) * N + col] = (f16)quick_gelu(v);
                }
            }
        }
    }
}

// ---------------- LayerNorm + weighted top-4 combine ----------------
__global__ void ln_combine_k(const f16* __restrict__ y16, const float* __restrict__ lng,
                             const float* __restrict__ lnb, const int* __restrict__ eids,
                             const int* __restrict__ slots, const float* __restrict__ gatew,
                             const int* __restrict__ offp, float* __restrict__ out) {
    int b = blockIdx.x, t = threadIdx.x;
    int lane = t & 63, w = t >> 6;
    __shared__ float red[4][2];
    float o[4] = {0.f, 0.f, 0.f, 0.f};
    int c0 = t * 4;
    for (int k = 0; k < NK; k++) {
        int e = eids[b * NK + k];
        long r = offp[e] + slots[b * NK + k];
        float wk = gatew[b * NK + k];
        f16x4 hv = *(const f16x4*)(y16 + r * NC + c0);
        float v[4];
        #pragma unroll
        for (int j = 0; j < 4; j++) v[j] = (float)hv[j];
        float s = v[0] + v[1] + v[2] + v[3];
        float ss = v[0] * v[0] + v[1] * v[1] + v[2] * v[2] + v[3] * v[3];
        #pragma unroll
        for (int off = 32; off; off >>= 1) { s += __shfl_down(s, off); ss += __shfl_down(ss, off); }
        if (lane == 0) { red[w][0] = s; red[w][1] = ss; }
        __syncthreads();
        float S  = red[0][0] + red[1][0] + red[2][0] + red[3][0];
        float SS = red[0][1] + red[1][1] + red[2][1] + red[3][1];
        float mu = S * (1.f / NC);
        float var = SS * (1.f / NC) - mu * mu;
        float rs = rsqrtf(var + 1e-6f);
        #pragma unroll
        for (int j = 0; j < 4; j++) {
            float g  = lng[(long)e * NC + c0 + j];
            float bb = lnb[(long)e * NC + c0 + j];
            o[j] += wk * ((v[j] - mu) * rs * g + bb);
        }
        __syncthreads();
    }
    float4 ov = {o[0], o[1], o[2], o[3]};
    ((float4*)(out + (long)b * NC))[t] = ov;
}

extern "C" void kernel_launch(void* const* d_in, const int* in_sizes, int n_in,
                              void* d_out, int out_size, void* d_ws, size_t ws_size,
                              hipStream_t stream) {
    const float* x   = (const float*)d_in[0];
    const float* W1  = (const float*)d_in[1];
    const float* b1  = (const float*)d_in[2];
    const float* W2  = (const float*)d_in[3];
    const float* b2  = (const float*)d_in[4];
    const float* lng = (const float*)d_in[5];
    const float* lnb = (const float*)d_in[6];
    const float* Wg  = (const float*)d_in[7];
    const float* bg  = (const float*)d_in[8];
    float* out = (float*)d_out;

    char* ws = (char*)d_ws;
    size_t o = 0;
    auto take = [&](size_t bytes) { char* p = ws + o; o += (bytes + 255) & ~(size_t)255; return p; };
    f16*   x16    = (f16*)take((size_t)NB * NC * 2);
    f16*   w1t    = (f16*)take((size_t)NE * NH * NC * 2);   // [E][H][C]
    f16*   w2t    = (f16*)take((size_t)NE * NC * NH * 2);   // [E][C][H]
    f16*   h16    = (f16*)take((size_t)ROWCAP * NH * 2);
    f16*   y16    = (f16*)take((size_t)ROWCAP * NC * 2);
    int*   tokmap = (int*)take((size_t)NE * NB * 4);
    int*   eids   = (int*)take((size_t)NB * NK * 4);
    int*   slots  = (int*)take((size_t)NB * NK * 4);
    float* gatew  = (float*)take((size_t)NB * NK * 4);
    int*   counts = (int*)take(256);
    int*   offp   = (int*)take(256);

    hipMemsetAsync(counts, 0, NE * sizeof(int), stream);
    transpose_cast_k<<<dim3(NH / 32, NC / 32, NE), 256, 0, stream>>>(W1, w1t, NC, NH);
    transpose_cast_k<<<dim3(NC / 32, NH / 32, NE), 256, 0, stream>>>(W2, w2t, NH, NC);
    gating_k<<<NB, 256, 0, stream>>>(x, Wg, bg, counts, tokmap, eids, slots, gatew, x16);
    offsets_k<<<1, 64, 0, stream>>>(counts, offp);
    gemm_f16<<<dim3(64, NH / 128, NE), 256, 0, stream>>>(x16, w1t, b1, h16, counts, offp, tokmap, NC, NH, 1);
    gemm_f16<<<dim3(64, NC / 128, NE), 256, 0, stream>>>(h16, w2t, b2, y16, counts, offp, tokmap, NH, NC, 0);
    ln_combine_k<<<NB, 256, 0, stream>>>(y16, lng, lnb, eids, slots, gatew, offp, out);
}

// Round 3
// 1862.937 us; speedup vs baseline: 1.0660x; 1.0314x over previous
//
#include <hip/hip_runtime.h>

#define NB 8192   // tokens
#define NC 1024   // model dim
#define NE 8      // experts
#define NK 4      // top-k
#define NH 4096   // hidden dim
constexpr int ROWCAP = NB * NK + NE * 128;  // padded routed-row capacity

typedef _Float16 f16;
typedef _Float16 f16x8 __attribute__((ext_vector_type(8)));
typedef _Float16 f16x4 __attribute__((ext_vector_type(4)));
typedef float    f32x4 __attribute__((ext_vector_type(4)));

__device__ __forceinline__ void async_cp16(const f16* g, f16* l) {
    __builtin_amdgcn_global_load_lds((const __attribute__((address_space(1))) void*)g,
                                     (__attribute__((address_space(3))) void*)l, 16, 0, 0);
}

__device__ __forceinline__ float quick_gelu(float v) {
    return v / (1.f + __expf(-1.702f * v));
}

// ------------- transpose + cast: in [E][R][S] fp32 -> out [E][S][R] fp16 -------------
__global__ void transpose_cast_k(const float* __restrict__ in, f16* __restrict__ out,
                                 int R, int S) {
    __shared__ f16 tile[32][33];
    int e = blockIdx.z;
    long base = (long)e * R * S;
    int s0 = blockIdx.x * 32, r0 = blockIdx.y * 32;
    int tx = threadIdx.x & 31, ty = threadIdx.x >> 5;  // 32 x 8
    #pragma unroll
    for (int i = 0; i < 32; i += 8)
        tile[ty + i][tx] = (f16)in[base + (long)(r0 + ty + i) * S + s0 + tx];
    __syncthreads();
    #pragma unroll
    for (int i = 0; i < 32; i += 8)
        out[base + (long)(s0 + ty + i) * R + r0 + tx] = tile[tx][ty + i];
}

// ---- gating: logits -> softmax -> top4 -> slot assignment; also casts x -> fp16 ----
__global__ void gating_k(const float* __restrict__ x, const float* __restrict__ Wg,
                         const float* __restrict__ bg, int* __restrict__ counts,
                         int* __restrict__ tokmap, int* __restrict__ eids,
                         int* __restrict__ slots, float* __restrict__ gatew,
                         f16* __restrict__ x16) {
    int b = blockIdx.x, t = threadIdx.x;
    float acc[NE] = {};
    float4 xv = ((const float4*)(x + (long)b * NC))[t];
    f16x4 hx = { (f16)xv.x, (f16)xv.y, (f16)xv.z, (f16)xv.w };
    ((f16x4*)(x16 + (long)b * NC))[t] = hx;
    const float* wr = Wg + (long)t * 4 * NE;
    #pragma unroll
    for (int j = 0; j < 4; j++) {
        float xj = ((const float*)&xv)[j];
        #pragma unroll
        for (int e2 = 0; e2 < NE; e2++) acc[e2] += xj * wr[j * NE + e2];
    }
    #pragma unroll
    for (int e2 = 0; e2 < NE; e2++)
        #pragma unroll
        for (int off = 32; off; off >>= 1) acc[e2] += __shfl_down(acc[e2], off);
    __shared__ float red[4][NE];
    int lane = t & 63, w = t >> 6;
    if (lane == 0)
        for (int e2 = 0; e2 < NE; e2++) red[w][e2] = acc[e2];
    __syncthreads();
    if (t == 0) {
        float l[NE];
        float m = -1e30f;
        for (int e2 = 0; e2 < NE; e2++) {
            l[e2] = red[0][e2] + red[1][e2] + red[2][e2] + red[3][e2] + bg[e2];
            m = fmaxf(m, l[e2]);
        }
        float p[NE], sum = 0.f;
        for (int e2 = 0; e2 < NE; e2++) { p[e2] = __expf(l[e2] - m); sum += p[e2]; }
        float inv = 1.f / sum;
        for (int e2 = 0; e2 < NE; e2++) p[e2] *= inv;
        bool taken[NE] = {};
        for (int k = 0; k < NK; k++) {
            int be = 0; float bv = -1e30f;
            for (int e2 = 0; e2 < NE; e2++)
                if (!taken[e2] && p[e2] > bv) { bv = p[e2]; be = e2; }
            taken[be] = true;
            int slot = atomicAdd(&counts[be], 1);
            tokmap[be * NB + slot] = b;
            eids[b * NK + k] = be;
            slots[b * NK + k] = slot;
            gatew[b * NK + k] = bv;
        }
    }
}

// ---------------- padded prefix offsets ----------------
__global__ void offsets_k(const int* __restrict__ counts, int* __restrict__ offp) {
    if (threadIdx.x == 0 && blockIdx.x == 0) {
        int o = 0;
        for (int e = 0; e < NE; e++) { offp[e] = o; o += ((counts[e] + 127) >> 7) << 7; }
    }
}

// ---------------- GEMM: Out[row,n] = gelu(sum_k A[row,k]*Bt[e,n,k] + bias[e,n]) ----------------
// Double-buffered LDS (prefetch iter k+1 into the other parity before computing iter k;
// the global_load_lds queue stays in flight across the whole compute phase, so the
// single barrier drain at iter end pays latency - compute instead of full latency).
// XOR chunk swizzle keeps fragment ds_read_b128 conflict-free (see round-1 notes).
// Epilogue round-trips the C-tile through LDS so global stores are full 64B lines
// (kills read-for-ownership amplification seen as +190MB FETCH / 1.8x WRITE).
__global__ __launch_bounds__(256) void gemm_f16(
    const f16* __restrict__ A, const f16* __restrict__ Bt,
    const float* __restrict__ bias, f16* __restrict__ Out,
    const int* __restrict__ counts, const int* __restrict__ offp,
    const int* __restrict__ tokmap, int Kd, int N, int gather) {
    int e = blockIdx.z;
    int cnt = counts[e];
    int m0 = blockIdx.x << 7;
    if (m0 >= cnt) return;
    int n0 = blockIdx.y << 7;
    int base = offp[e];

    // per parity: A tile 4096 f16 | B tile 4096 f16  (16 KB); 2 parities = 32 KB
    __shared__ __align__(16) f16 smem[16384];

    int t = threadIdx.x;
    int lane = t & 63;
    int w = t >> 6;
    int wm = (w >> 1) << 6, wn = (w & 1) << 6;

    // staging: thread t fills LDS slot (row=t>>2, slot=t&3); global source chunk is
    // XOR-permuted so LDS dests stay lane-contiguous (global_load_lds constraint).
    int sr = m0 + (t >> 2);
    int sc = (((t & 3) ^ ((t >> 3) & 3)) << 3);
    int ca = sr < cnt - 1 ? sr : cnt - 1;
    int cb = sr + 64 < cnt - 1 ? sr + 64 : cnt - 1;
    long arow0, arow1;
    if (gather) { arow0 = tokmap[e * NB + ca]; arow1 = tokmap[e * NB + cb]; }
    else        { arow0 = base + ca;           arow1 = base + cb; }
    const f16* ap0 = A + arow0 * (long)Kd + sc;
    const f16* ap1 = A + arow1 * (long)Kd + sc;
    const f16* bp0 = Bt + ((long)e * N + n0 + (t >> 2)) * (long)Kd + sc;
    const f16* bp1 = bp0 + (long)64 * Kd;

    auto stage = [&](int q) {
        f16* d = smem + (q << 13) + (t << 3);
        async_cp16(ap0, d);        ap0 += 32;
        async_cp16(ap1, d + 2048); ap1 += 32;
        async_cp16(bp0, d + 4096); bp0 += 32;
        async_cp16(bp1, d + 6144); bp1 += 32;
    };

    f32x4 acc[4][4] = {};
    int ml = lane & 15;
    // fragment read slot: (kq ^ swz(row)); row offsets are multiples of 16 so the
    // swizzle term is the per-lane constant (ml>>1)&3.
    int sxq = (((lane >> 4) ^ ((ml >> 1) & 3)) << 3);
    int aoff = (wm + ml) * 32 + sxq;         // + mi*512 per fragment
    int boff = (wn + ml) * 32 + sxq + 4096;  // + ni*512 per fragment

    int nIter = Kd >> 5;
    stage(0);
    __syncthreads();
    for (int it = 0; it < nIter; ++it) {
        int p = it & 1;
        if (it + 1 < nIter) stage(p ^ 1);   // async prefetch, in flight during MFMA
        const f16* sb = smem + (p << 13);
        f16x8 af[4], bf[4];
        #pragma unroll
        for (int mi = 0; mi < 4; mi++) af[mi] = *(const f16x8*)(sb + aoff + mi * 512);
        #pragma unroll
        for (int ni = 0; ni < 4; ni++) bf[ni] = *(const f16x8*)(sb + boff + ni * 512);
        #pragma unroll
        for (int mi = 0; mi < 4; mi++)
            #pragma unroll
            for (int ni = 0; ni < 4; ni++)
                acc[mi][ni] = __builtin_amdgcn_mfma_f32_16x16x32_f16(af[mi], bf[ni], acc[mi][ni], 0, 0, 0);
        __syncthreads();
    }

    // ---- epilogue: bias + gelu -> LDS half-tile -> coalesced 16B stores ----
    const int EP = 136;   // f16 per row (272 B, 16B-aligned; quad rows land 16 banks apart)
    int rq = (lane >> 4) << 2;
    #pragma unroll
    for (int h = 0; h < 2; ++h) {
        if (wm == h * 64) {
            #pragma unroll
            for (int ni = 0; ni < 4; ni++) {
                int col = wn + ni * 16 + ml;
                float bv = bias[(long)e * N + n0 + col];
                #pragma unroll
                for (int mi = 0; mi < 4; mi++) {
                    #pragma unroll
                    for (int rr = 0; rr < 4; rr++) {
                        int lr = mi * 16 + rq + rr;   // 0..63
                        smem[lr * EP + col] = (f16)quick_gelu(acc[mi][ni][rr] + bv);
                    }
                }
            }
        }
        __syncthreads();
        int r = t >> 2;
        int grow = m0 + h * 64 + r;
        if (grow < cnt) {
            long gbase = (long)(base + grow) * N + n0;
            #pragma unroll
            for (int j = 0; j < 4; j++) {
                int cc = ((t & 3) + 4 * j) << 3;
                *(f16x8*)(Out + gbase + cc) = *(const f16x8*)&smem[r * EP + cc];
            }
        }
        __syncthreads();
    }
}

// ---------------- LayerNorm + weighted top-4 combine ----------------
__global__ void ln_combine_k(const f16* __restrict__ y16, const float* __restrict__ lng,
                             const float* __restrict__ lnb, const int* __restrict__ eids,
                             const int* __restrict__ slots, const float* __restrict__ gatew,
                             const int* __restrict__ offp, float* __restrict__ out) {
    int b = blockIdx.x, t = threadIdx.x;
    int lane = t & 63, w = t >> 6;
    __shared__ float red[4][2];
    float o[4] = {0.f, 0.f, 0.f, 0.f};
    int c0 = t * 4;
    for (int k = 0; k < NK; k++) {
        int e = eids[b * NK + k];
        long r = offp[e] + slots[b * NK + k];
        float wk = gatew[b * NK + k];
        f16x4 hv = *(const f16x4*)(y16 + r * NC + c0);
        float v[4];
        #pragma unroll
        for (int j = 0; j < 4; j++) v[j] = (float)hv[j];
        float s = v[0] + v[1] + v[2] + v[3];
        float ss = v[0] * v[0] + v[1] * v[1] + v[2] * v[2] + v[3] * v[3];
        #pragma unroll
        for (int off = 32; off; off >>= 1) { s += __shfl_down(s, off); ss += __shfl_down(ss, off); }
        if (lane == 0) { red[w][0] = s; red[w][1] = ss; }
        __syncthreads();
        float S  = red[0][0] + red[1][0] + red[2][0] + red[3][0];
        float SS = red[0][1] + red[1][1] + red[2][1] + red[3][1];
        float mu = S * (1.f / NC);
        float var = SS * (1.f / NC) - mu * mu;
        float rs = rsqrtf(var + 1e-6f);
        #pragma unroll
        for (int j = 0; j < 4; j++) {
            float g  = lng[(long)e * NC + c0 + j];
            float bb = lnb[(long)e * NC + c0 + j];
            o[j] += wk * ((v[j] - mu) * rs * g + bb);
        }
        __syncthreads();
    }
    float4 ov = {o[0], o[1], o[2], o[3]};
    ((float4*)(out + (long)b * NC))[t] = ov;
}

extern "C" void kernel_launch(void* const* d_in, const int* in_sizes, int n_in,
                              void* d_out, int out_size, void* d_ws, size_t ws_size,
                              hipStream_t stream) {
    const float* x   = (const float*)d_in[0];
    const float* W1  = (const float*)d_in[1];
    const float* b1  = (const float*)d_in[2];
    const float* W2  = (const float*)d_in[3];
    const float* b2  = (const float*)d_in[4];
    const float* lng = (const float*)d_in[5];
    const float* lnb = (const float*)d_in[6];
    const float* Wg  = (const float*)d_in[7];
    const float* bg  = (const float*)d_in[8];
    float* out = (float*)d_out;

    char* ws = (char*)d_ws;
    size_t o = 0;
    auto take = [&](size_t bytes) { char* p = ws + o; o += (bytes + 255) & ~(size_t)255; return p; };
    f16*   x16    = (f16*)take((size_t)NB * NC * 2);
    f16*   w1t    = (f16*)take((size_t)NE * NH * NC * 2);   // [E][H][C]
    f16*   w2t    = (f16*)take((size_t)NE * NC * NH * 2);   // [E][C][H]
    f16*   h16    = (f16*)take((size_t)ROWCAP * NH * 2);
    f16*   y16    = (f16*)take((size_t)ROWCAP * NC * 2);
    int*   tokmap = (int*)take((size_t)NE * NB * 4);
    int*   eids   = (int*)take((size_t)NB * NK * 4);
    int*   slots  = (int*)take((size_t)NB * NK * 4);
    float* gatew  = (float*)take((size_t)NB * NK * 4);
    int*   counts = (int*)take(256);
    int*   offp   = (int*)take(256);

    hipMemsetAsync(counts, 0, NE * sizeof(int), stream);
    transpose_cast_k<<<dim3(NH / 32, NC / 32, NE), 256, 0, stream>>>(W1, w1t, NC, NH);
    transpose_cast_k<<<dim3(NC / 32, NH / 32, NE), 256, 0, stream>>>(W2, w2t, NH, NC);
    gating_k<<<NB, 256, 0, stream>>>(x, Wg, bg, counts, tokmap, eids, slots, gatew, x16);
    offsets_k<<<1, 64, 0, stream>>>(counts, offp);
    gemm_f16<<<dim3(64, NH / 128, NE), 256, 0, stream>>>(x16, w1t, b1, h16, counts, offp, tokmap, NC, NH, 1);
    gemm_f16<<<dim3(64, NC / 128, NE), 256, 0, stream>>>(h16, w2t, b2, y16, counts, offp, tokmap, NH, NC, 0);
    ln_combine_k<<<NB, 256, 0, stream>>>(y16, lng, lnb, eids, slots, gatew, offp, out);
}